// Round 1
// baseline (377.694 us; speedup 1.0000x reference)
//
#include <hip/hip_runtime.h>
#include <math.h>

// FullyConnectedTree: eval-mode layers are purely affine =>
//   out = x @ (W0@W1@W2) + (a0@W1@W2 + a1@W2 + a2) = x@v + c
// Kernel 1 folds the 64x64x64x1 weight chain into v[64], c (-> d_ws).
// Kernel 2 is a memory-bound B x 64 matvec (256 MB read, 4 MB write).

__device__ __forceinline__ float sigm(float x) { return 1.0f / (1.0f + expf(-x)); }

__global__ void fold_weights(const float* __restrict__ el0, const float* __restrict__ el1,
                             const float* __restrict__ el2, const float* __restrict__ es0,
                             const float* __restrict__ es1, const float* __restrict__ es2,
                             const float* __restrict__ b0, const float* __restrict__ b1,
                             const float* __restrict__ b2, float* __restrict__ vc) {
    __shared__ float w2s[64];
    __shared__ float us[64];
    const int j = threadIdx.x;           // 0..63, single wave
    const float invT = 1.0f / 3.0f;

    // w2 = sigmoid(el2/T) * es2   (64,1)
    float w2 = sigm(el2[j] * invT) * es2[j];
    w2s[j] = w2;
    __syncthreads();

    // u = W1 @ w2, W1[j][k] = sigmoid(el1[j][k]/T)*es1[j][k]
    float u = 0.0f;
    for (int k = 0; k < 64; ++k)
        u += sigm(el1[j * 64 + k] * invT) * es1[j * 64 + k] * w2s[k];
    us[j] = u;
    __syncthreads();

    // v = W0 @ u
    float v = 0.0f;
    for (int k = 0; k < 64; ++k)
        v += sigm(el0[j * 64 + k] * invT) * es0[j * 64 + k] * us[k];
    vc[j] = v;

    // c = sum_j a0[j]*u[j] + sum_j a1[j]*w2[j] + a2
    float a0 = sigm(b0[j]) * 3.0f - 1.0f;
    float a1 = sigm(b1[j]) * 3.0f - 1.0f;
    float cpart = a0 * u + a1 * w2;
    #pragma unroll
    for (int m = 1; m < 64; m <<= 1) cpart += __shfl_xor(cpart, m, 64);
    if (j == 0) vc[64] = cpart + (sigm(b2[0]) * 3.0f - 1.0f);
}

// 16 lanes per row, one float4 per lane: each wave loads 1024 contiguous bytes
// (4 full rows) per iteration -> perfect coalescing. shfl_xor reduce within
// 16-lane groups; lane (l%16)==0 writes the row's output.
__global__ void matvec64(const float4* __restrict__ x4, const float* __restrict__ vc,
                         float* __restrict__ out, int B) {
    const int lane16 = threadIdx.x & 15;
    const float4 vv = reinterpret_cast<const float4*>(vc)[lane16];
    const float c = vc[64];

    const int tid = blockIdx.x * blockDim.x + threadIdx.x;
    const int nthreads = gridDim.x * blockDim.x;
    const int grp = tid >> 4;         // row handled this iteration
    const int ngrp = nthreads >> 4;

    for (int row = grp; row < B; row += ngrp) {
        const float4 xv = x4[row * 16 + lane16];
        float s = xv.x * vv.x + xv.y * vv.y + xv.z * vv.z + xv.w * vv.w;
        s += __shfl_xor(s, 1);
        s += __shfl_xor(s, 2);
        s += __shfl_xor(s, 4);
        s += __shfl_xor(s, 8);
        if (lane16 == 0) out[row] = s + c;
    }
}

extern "C" void kernel_launch(void* const* d_in, const int* in_sizes, int n_in,
                              void* d_out, int out_size, void* d_ws, size_t ws_size,
                              hipStream_t stream) {
    const float* x   = (const float*)d_in[0];
    const float* el0 = (const float*)d_in[1];
    const float* el1 = (const float*)d_in[2];
    const float* el2 = (const float*)d_in[3];
    const float* es0 = (const float*)d_in[4];
    const float* es1 = (const float*)d_in[5];
    const float* es2 = (const float*)d_in[6];
    const float* b0  = (const float*)d_in[7];
    const float* b1  = (const float*)d_in[8];
    const float* b2  = (const float*)d_in[9];
    float* out = (float*)d_out;
    float* vc  = (float*)d_ws;        // 65 floats: v[64] + c

    const int B = in_sizes[0] / 64;   // 1048576

    fold_weights<<<1, 64, 0, stream>>>(el0, el1, el2, es0, es1, es2, b0, b1, b2, vc);

    const int blocks = 8192;          // 256 thr = 16 rows/block/iter; grid-stride
    matvec64<<<blocks, 256, 0, stream>>>((const float4*)x, vc, out, B);
}

// Round 3
// 357.888 us; speedup vs baseline: 1.0553x; 1.0553x over previous
//
#include <hip/hip_runtime.h>
#include <math.h>

// FullyConnectedTree: eval-mode layers are purely affine =>
//   out = x @ (W0@W1@W2) + (a0@W1@W2 + a1@W2 + a2) = x@v + c
// Kernel 1 folds the 64x64x64x1 weight chain into v[64], c (-> d_ws).
// Kernel 2 is a memory-bound B x 64 matvec (256 MB read, 4 MB write).

using vf4 = __attribute__((ext_vector_type(4))) float;  // native vec for nontemporal builtins

__device__ __forceinline__ float sigm(float x) { return 1.0f / (1.0f + expf(-x)); }

// 256 threads: 4 threads per output node (quad-shuffle reduce), float4 weight
// loads. Bounds the fold to a few microseconds independent of unrolling.
__global__ __launch_bounds__(256) void fold_weights(
        const float* __restrict__ el0, const float* __restrict__ el1,
        const float* __restrict__ el2, const float* __restrict__ es0,
        const float* __restrict__ es1, const float* __restrict__ es2,
        const float* __restrict__ b0, const float* __restrict__ b1,
        const float* __restrict__ b2, float* __restrict__ vc) {
    __shared__ float w2s[64];
    __shared__ float us[64];
    const int t = threadIdx.x;            // 0..255
    const float invT = 1.0f / 3.0f;

    if (t < 64) w2s[t] = sigm(el2[t] * invT) * es2[t];
    __syncthreads();

    const int j = t >> 2;                 // output node 0..63
    const int q = t & 3;                  // quad slice 0..3 (k = q*16..q*16+15)

    // u = W1 @ w2, W1[j][k] = sigmoid(el1[j][k]/T)*es1[j][k]
    {
        const float4* l4 = reinterpret_cast<const float4*>(el1 + j * 64 + q * 16);
        const float4* s4 = reinterpret_cast<const float4*>(es1 + j * 64 + q * 16);
        const float4* w4 = reinterpret_cast<const float4*>(&w2s[q * 16]);
        float p = 0.0f;
        #pragma unroll
        for (int i = 0; i < 4; ++i) {
            float4 l = l4[i], s = s4[i], w = w4[i];
            p += sigm(l.x * invT) * s.x * w.x + sigm(l.y * invT) * s.y * w.y
               + sigm(l.z * invT) * s.z * w.z + sigm(l.w * invT) * s.w * w.w;
        }
        p += __shfl_xor(p, 1);
        p += __shfl_xor(p, 2);
        if (q == 0) us[j] = p;
    }
    __syncthreads();

    // v = W0 @ u
    {
        const float4* l4 = reinterpret_cast<const float4*>(el0 + j * 64 + q * 16);
        const float4* s4 = reinterpret_cast<const float4*>(es0 + j * 64 + q * 16);
        const float4* u4 = reinterpret_cast<const float4*>(&us[q * 16]);
        float p = 0.0f;
        #pragma unroll
        for (int i = 0; i < 4; ++i) {
            float4 l = l4[i], s = s4[i], u = u4[i];
            p += sigm(l.x * invT) * s.x * u.x + sigm(l.y * invT) * s.y * u.y
               + sigm(l.z * invT) * s.z * u.z + sigm(l.w * invT) * s.w * u.w;
        }
        p += __shfl_xor(p, 1);
        p += __shfl_xor(p, 2);
        if (q == 0) vc[j] = p;
    }

    // c = sum_j a0[j]*u[j] + sum_j a1[j]*w2[j] + a2   (wave 0 only)
    if (t < 64) {
        float a0 = sigm(b0[t]) * 3.0f - 1.0f;
        float a1 = sigm(b1[t]) * 3.0f - 1.0f;
        float cp = a0 * us[t] + a1 * w2s[t];
        #pragma unroll
        for (int m = 1; m < 64; m <<= 1) cp += __shfl_xor(cp, m, 64);
        if (t == 0) vc[64] = cp + (sigm(b2[0]) * 3.0f - 1.0f);
    }
}

// 16 lanes per row, one float4 per lane: each wave loads 1024 contiguous bytes
// (4 full rows) per iteration. Nontemporal loads (x is streamed once), 2-way
// independent unroll for load + DS-pipe ILP.
__global__ __launch_bounds__(256) void matvec64(
        const vf4* __restrict__ x4, const float* __restrict__ vc,
        float* __restrict__ out, int B) {
    const int lane16 = threadIdx.x & 15;
    const float4 vv = reinterpret_cast<const float4*>(vc)[lane16];
    const float c = vc[64];

    const int tid = blockIdx.x * blockDim.x + threadIdx.x;
    const int nthreads = gridDim.x * blockDim.x;
    const int grp = tid >> 4;         // row handled this iteration
    const int ngrp = nthreads >> 4;

    for (int row = grp; row < B; row += 2 * ngrp) {
        const int row2 = row + ngrp;
        vf4 xa = __builtin_nontemporal_load(&x4[row * 16 + lane16]);
        float sa = xa.x * vv.x + xa.y * vv.y + xa.z * vv.z + xa.w * vv.w;
        float sb = 0.0f;
        if (row2 < B) {
            vf4 xb = __builtin_nontemporal_load(&x4[row2 * 16 + lane16]);
            sb = xb.x * vv.x + xb.y * vv.y + xb.z * vv.z + xb.w * vv.w;
        }
        sa += __shfl_xor(sa, 1);  sb += __shfl_xor(sb, 1);
        sa += __shfl_xor(sa, 2);  sb += __shfl_xor(sb, 2);
        sa += __shfl_xor(sa, 4);  sb += __shfl_xor(sb, 4);
        sa += __shfl_xor(sa, 8);  sb += __shfl_xor(sb, 8);
        if (lane16 == 0) {
            __builtin_nontemporal_store(sa + c, &out[row]);
            if (row2 < B) __builtin_nontemporal_store(sb + c, &out[row2]);
        }
    }
}

extern "C" void kernel_launch(void* const* d_in, const int* in_sizes, int n_in,
                              void* d_out, int out_size, void* d_ws, size_t ws_size,
                              hipStream_t stream) {
    const float* x   = (const float*)d_in[0];
    const float* el0 = (const float*)d_in[1];
    const float* el1 = (const float*)d_in[2];
    const float* el2 = (const float*)d_in[3];
    const float* es0 = (const float*)d_in[4];
    const float* es1 = (const float*)d_in[5];
    const float* es2 = (const float*)d_in[6];
    const float* b0  = (const float*)d_in[7];
    const float* b1  = (const float*)d_in[8];
    const float* b2  = (const float*)d_in[9];
    float* out = (float*)d_out;
    float* vc  = (float*)d_ws;        // 65 floats: v[64] + c

    const int B = in_sizes[0] / 64;   // 1048576

    fold_weights<<<1, 256, 0, stream>>>(el0, el1, el2, es0, es1, es2, b0, b1, b2, vc);

    const int blocks = 8192;          // 16 rows/block/iter; 8 rows per thread total
    matvec64<<<blocks, 256, 0, stream>>>((const vf4*)x, vc, out, B);
}